// Round 1
// baseline (401.728 us; speedup 1.0000x reference)
//
#include <hip/hip_runtime.h>

#define Bn 64
#define Dn 128
#define Ln 512
#define Hn 4

// ---------------- K0a: transpose X[l][b][e] -> XT[b][e][l] ----------------
__global__ __launch_bounds__(256) void tr_x(const float* __restrict__ X,
                                            float* __restrict__ XT) {
  __shared__ float tile[32][33];
  int l0 = blockIdx.x * 32, e0 = blockIdx.y * 32, b = blockIdx.z;
  int t = threadIdx.x;
  int c = t & 31, r0 = t >> 5;  // 8 row-groups
#pragma unroll
  for (int p = 0; p < 4; ++p) {
    int r = p * 8 + r0;
    tile[r][c] = X[((l0 + r) * Bn + b) * Dn + e0 + c];  // coalesced over c
  }
  __syncthreads();
#pragma unroll
  for (int p = 0; p < 4; ++p) {
    int r = p * 8 + r0;
    XT[(b * Dn + e0 + r) * Ln + l0 + c] = tile[c][r];   // coalesced over c
  }
}

// ---------------- K0b: WUT[h][e][d] = W_U[h][d][e] ----------------
__global__ __launch_bounds__(256) void tr_wu(const float* __restrict__ WU,
                                             float* __restrict__ WUT) {
  int f = blockIdx.x * 256 + threadIdx.x;   // 65536 total
  int h = f >> 14, e = (f >> 7) & 127, d = f & 127;
  WUT[f] = WU[(h * Dn + d) * Dn + e];
}

// ---------------- K1: masked row/col maxes of S = X1 @ (WU @ X2^T) -------
// block = (b, h, mt) ; mt = 64-wide m tile. 256 threads, ~73 KB LDS -> 2 blk/CU.
#define FMA4(accrow, s, v4) \
  { accrow[0] += (s) * (v4).x; accrow[1] += (s) * (v4).y; \
    accrow[2] += (s) * (v4).z; accrow[3] += (s) * (v4).w; }

__global__ __launch_bounds__(256, 2) void k1(
    const float* __restrict__ X1T, const float* __restrict__ X2T,
    const float* __restrict__ WUT, const int* __restrict__ raw1,
    const int* __restrict__ raw2, float* __restrict__ s1p,
    float* __restrict__ s2) {
  int blk = blockIdx.x;
  int mt = blk & 7;
  int h = (blk >> 3) & 3;
  int b = blk >> 5;
  int t = threadIdx.x;

  __shared__ float shA[128 * 68];   // X2T tile (phase1), then X1T tiles (phase2)
  __shared__ float zt[128 * 68];    // ZT[d][m], stride 68
  __shared__ float mask1[512];      // 10000 * (raw1==PAD)
  __shared__ float mask2[64];
  __shared__ float cmw[4][64];      // per-wave colmax partials
  __shared__ float cmrun[64];       // running colmax across l-tiles

  for (int i = t; i < 512; i += 256)
    mask1[i] = (raw1[i * Bn + b] == 0) ? 10000.0f : 0.0f;
  if (t < 64) {
    mask2[t] = (raw2[(mt * 64 + t) * Bn + b] == 0) ? 10000.0f : 0.0f;
    cmrun[t] = -3.0e38f;
  }

  // ---- stage X2T tile [e'=128][m=64], stride 68 (conflict-free b128 R/W)
  {
    const float* src = X2T + (b * Dn) * Ln + mt * 64;
#pragma unroll
    for (int k = 0; k < 8; ++k) {
      int idx = k * 256 + t;           // 2048 float4s
      int e = idx >> 4, mq = idx & 15;
      *(float4*)(shA + e * 68 + mq * 4) =
          *(const float4*)(src + e * Ln + mq * 4);
    }
  }
  __syncthreads();

  // ---- phase 1: ZT[d][m] = sum_e' WUT[h][e'][d] * X2T[e'][m]
  {
    int dg = t >> 4, mg = t & 15;   // 8 d's, 4 m's per thread
    float acc[8][4] = {};
    const float* wbase = WUT + (h * Dn) * Dn + dg * 8;
#pragma unroll 4
    for (int e = 0; e < 128; ++e) {
      float4 wa = *(const float4*)(wbase + e * Dn);
      float4 wb = *(const float4*)(wbase + e * Dn + 4);
      float4 xv = *(const float4*)(shA + e * 68 + mg * 4);
      FMA4(acc[0], wa.x, xv); FMA4(acc[1], wa.y, xv);
      FMA4(acc[2], wa.z, xv); FMA4(acc[3], wa.w, xv);
      FMA4(acc[4], wb.x, xv); FMA4(acc[5], wb.y, xv);
      FMA4(acc[6], wb.z, xv); FMA4(acc[7], wb.w, xv);
    }
#pragma unroll
    for (int i = 0; i < 8; ++i)
      *(float4*)(zt + (dg * 8 + i) * 68 + mg * 4) =
          make_float4(acc[i][0], acc[i][1], acc[i][2], acc[i][3]);
  }

  // ---- phase 2: per l-tile of 64, dot products + masked maxes
  int bh = b * 4 + h;
  for (int lt = 0; lt < 8; ++lt) {
    __syncthreads();  // protect shA overwrite (also covers zt write on lt==0)
    const float* src = X1T + (b * Dn) * Ln + lt * 64;
#pragma unroll
    for (int k = 0; k < 8; ++k) {
      int idx = k * 256 + t;
      int e = idx >> 4, lq = idx & 15;
      *(float4*)(shA + e * 68 + lq * 4) =
          *(const float4*)(src + e * Ln + lq * 4);
    }
    __syncthreads();

    int lg = t >> 4, mg = t & 15;   // 4 l's, 4 m's per thread
    float acc[4][4] = {};
#pragma unroll 4
    for (int d = 0; d < 128; ++d) {
      float4 xv = *(const float4*)(shA + d * 68 + lg * 4);
      float4 zv = *(const float4*)(zt + d * 68 + mg * 4);
      FMA4(acc[0], xv.x, zv); FMA4(acc[1], xv.y, zv);
      FMA4(acc[2], xv.z, zv); FMA4(acc[3], xv.w, zv);
    }

    // rowmax over this block's 64 m (mask2), reduce across mg (bits 0..3)
    float rm[4];
#pragma unroll
    for (int i = 0; i < 4; ++i) {
      float v = acc[i][0] - mask2[mg * 4 + 0];
      v = fmaxf(v, acc[i][1] - mask2[mg * 4 + 1]);
      v = fmaxf(v, acc[i][2] - mask2[mg * 4 + 2]);
      v = fmaxf(v, acc[i][3] - mask2[mg * 4 + 3]);
      rm[i] = v;
    }
#pragma unroll
    for (int off = 1; off < 16; off <<= 1)
#pragma unroll
      for (int i = 0; i < 4; ++i) rm[i] = fmaxf(rm[i], __shfl_xor(rm[i], off));
    if (mg == 0)
      *(float4*)(s1p + ((bh * 8 + mt) * 512) + lt * 64 + lg * 4) =
          make_float4(rm[0], rm[1], rm[2], rm[3]);

    // colmax over these 4 l's (mask1), reduce across lg-in-wave (bits 4,5)
    int lbase = lt * 64 + lg * 4;
    float cm[4];
#pragma unroll
    for (int j = 0; j < 4; ++j) {
      float v = acc[0][j] - mask1[lbase + 0];
      v = fmaxf(v, acc[1][j] - mask1[lbase + 1]);
      v = fmaxf(v, acc[2][j] - mask1[lbase + 2]);
      v = fmaxf(v, acc[3][j] - mask1[lbase + 3]);
      cm[j] = v;
    }
#pragma unroll
    for (int off = 16; off < 64; off <<= 1)
#pragma unroll
      for (int j = 0; j < 4; ++j) cm[j] = fmaxf(cm[j], __shfl_xor(cm[j], off));
    int w = t >> 6;
    if ((t & 63) < 16)   // lg-local == 0 lanes; their mg spans 0..15
      *(float4*)(&cmw[w][mg * 4]) = make_float4(cm[0], cm[1], cm[2], cm[3]);
    __syncthreads();
    if (t < 64) {
      float m = fmaxf(fmaxf(cmw[0][t], cmw[1][t]), fmaxf(cmw[2][t], cmw[3][t]));
      cmrun[t] = fmaxf(cmrun[t], m);
    }
  }
  __syncthreads();
  if (t < 64) s2[bh * 512 + mt * 64 + t] = cmrun[t];
}

// ---------------- K2: tanh -> softmax -> a out, readout r ----------------
__global__ __launch_bounds__(256) void k2(
    const float* __restrict__ s1p, const float* __restrict__ s2,
    const float* __restrict__ X1, const float* __restrict__ X2,
    float* __restrict__ out, float* __restrict__ rws) {
  int blk = blockIdx.x;          // 0..511
  int side = blk >> 8, bh = blk & 255;
  int b = bh >> 2;
  int t = threadIdx.x;
  __shared__ float a[512];
  __shared__ float red[256];

  for (int i = t; i < 512; i += 256) {
    float v;
    if (side == 0) {
      float m = -3.0e38f;
#pragma unroll
      for (int mt = 0; mt < 8; ++mt) m = fmaxf(m, s1p[(bh * 8 + mt) * 512 + i]);
      v = m;
    } else {
      v = s2[bh * 512 + i];
    }
    a[i] = tanhf(v);
  }
  __syncthreads();
  // max
  red[t] = fmaxf(a[t], a[t + 256]);
  __syncthreads();
  for (int s = 128; s > 0; s >>= 1) {
    if (t < s) red[t] = fmaxf(red[t], red[t + s]);
    __syncthreads();
  }
  float mx = red[0];
  __syncthreads();
  float e0 = expf(a[t] - mx), e1 = expf(a[t + 256] - mx);
  red[t] = e0 + e1;
  __syncthreads();
  for (int s = 128; s > 0; s >>= 1) {
    if (t < s) red[t] += red[t + s];
    __syncthreads();
  }
  float inv = 1.0f / red[0];
  __syncthreads();
  a[t] = e0 * inv;
  a[t + 256] = e1 * inv;
  __syncthreads();

  int aoff = (side == 0 ? 16384 : 147456) + bh * 512;
  out[aoff + t] = a[t];
  out[aoff + t + 256] = a[t + 256];

  // r[d] = sum_l a[l] * X[l][b][d]   (coalesced over d)
  const float* X = (side == 0) ? X1 : X2;
  int d = t & 127, part = t >> 7;
  float acc = 0.0f;
  for (int l = part; l < 512; l += 2) acc += a[l] * X[(l * Bn + b) * Dn + d];
  __syncthreads();
  red[t] = acc;
  __syncthreads();
  if (t < 128) rws[side * 32768 + bh * 128 + t] = red[t] + red[t + 128];
}

// ---------------- K3: combine hops ----------------
__global__ __launch_bounds__(128) void k3(const float* __restrict__ rws,
                                          const float* __restrict__ Wipm,
                                          float* __restrict__ out) {
  int b = blockIdx.x, t = threadIdx.x;  // t = d
  __shared__ float r2l[4][128];
  __shared__ float tsum[2][4];
  float r1h[4], r2h[4];
#pragma unroll
  for (int h = 0; h < 4; ++h) {
    r1h[h] = rws[(b * 4 + h) * 128 + t];
    r2h[h] = rws[32768 + (b * 4 + h) * 128 + t];
    r2l[h][t] = r2h[h];
  }
  __syncthreads();
  float p[4] = {0, 0, 0, 0};
  for (int e = 0; e < 128; ++e) {
    float w = Wipm[t * 128 + e];
#pragma unroll
    for (int h = 0; h < 4; ++h) p[h] += w * r2l[h][e];
  }
#pragma unroll
  for (int h = 0; h < 4; ++h) p[h] *= r1h[h];
#pragma unroll
  for (int off = 1; off < 64; off <<= 1)
#pragma unroll
    for (int h = 0; h < 4; ++h) p[h] += __shfl_xor(p[h], off);
  if ((t & 63) == 0)
#pragma unroll
    for (int h = 0; h < 4; ++h) tsum[t >> 6][h] = p[h];
  __syncthreads();
  float ad[4], mx = -3.0e38f;
#pragma unroll
  for (int h = 0; h < 4; ++h) {
    float v = tanhf(tsum[0][h] + tsum[1][h]);
    ad[h] = v;
    mx = fmaxf(mx, v);
  }
  float s = 0.0f;
#pragma unroll
  for (int h = 0; h < 4; ++h) { ad[h] = expf(ad[h] - mx); s += ad[h]; }
  float inv = 1.0f / s;
#pragma unroll
  for (int h = 0; h < 4; ++h) ad[h] *= inv;
  if (t < 4) out[278528 + b * 4 + t] = ad[t];
  float f1 = 0.0f, f2 = 0.0f;
#pragma unroll
  for (int h = 0; h < 4; ++h) { f1 += ad[h] * r1h[h]; f2 += ad[h] * r2h[h]; }
  out[b * 128 + t] = f1;
  out[8192 + b * 128 + t] = f2;
}

extern "C" void kernel_launch(void* const* d_in, const int* in_sizes, int n_in,
                              void* d_out, int out_size, void* d_ws,
                              size_t ws_size, hipStream_t stream) {
  (void)in_sizes; (void)n_in; (void)out_size; (void)ws_size;
  const float* x1 = (const float*)d_in[0];
  const float* x2 = (const float*)d_in[1];
  const int* raw1 = (const int*)d_in[2];
  const int* raw2 = (const int*)d_in[3];
  const float* wu = (const float*)d_in[4];
  const float* wipm = (const float*)d_in[5];
  float* out = (float*)d_out;
  float* w = (float*)d_ws;
  // ws layout (floats): needs ~38.8 MB total
  float* wut = w;                  // 65536
  float* s1p = w + 65536;          // 1048576  [bh][mt][l]
  float* s2 = w + 1114112;         // 131072   [bh][m]
  float* rws = w + 1245184;        // 65536    [side][bh][d]
  float* x1t = w + 1310720;        // 4194304  [b][d][l]
  float* x2t = w + 5505024;        // 4194304

  tr_x<<<dim3(16, 4, 64), 256, 0, stream>>>(x1, x1t);
  tr_x<<<dim3(16, 4, 64), 256, 0, stream>>>(x2, x2t);
  tr_wu<<<256, 256, 0, stream>>>(wu, wut);
  k1<<<2048, 256, 0, stream>>>(x1t, x2t, wut, raw1, raw2, s1p, s2);
  k2<<<512, 256, 0, stream>>>(s1p, s2, x1, x2, out, rws);
  k3<<<64, 128, 0, stream>>>(rws, wipm, out);
}

// Round 2
// 193.217 us; speedup vs baseline: 2.0792x; 2.0792x over previous
//
#include <hip/hip_runtime.h>

#define Bn 64
#define Dn 128
#define Ln 512
#define Hn 4

typedef __attribute__((ext_vector_type(8))) short short8;
typedef __attribute__((ext_vector_type(4))) float f32x4;

__device__ __forceinline__ unsigned short f2bf(float x) {
  unsigned int u = __float_as_uint(x);
  unsigned int r = (u + 0x7FFFu + ((u >> 16) & 1u)) >> 16;  // RNE
  return (unsigned short)r;
}
__device__ __forceinline__ float bf2f(unsigned short h) {
  return __uint_as_float(((unsigned int)h) << 16);
}
__device__ __forceinline__ void split8(const float* xs, short8& hi, short8& lo) {
#pragma unroll
  for (int j = 0; j < 8; ++j) {
    unsigned short h = f2bf(xs[j]);
    float l = xs[j] - bf2f(h);
    hi[j] = (short)h;
    lo[j] = (short)f2bf(l);
  }
}
__device__ __forceinline__ void gll16(const void* g, void* l) {
  __builtin_amdgcn_global_load_lds(
      (const __attribute__((address_space(1))) void*)g,
      (__attribute__((address_space(3))) void*)l, 16, 0, 0);
}

// ---------------- kz: Z[bh][m][d] = sum_e X2[m,b,e] WU[h,d,e], split-bf16
// images (chunk-swizzled) for k1's B staging. grid: b*16 + mt*4 + h --------
__global__ __launch_bounds__(256) void kz(const float* __restrict__ X2,
                                          const float* __restrict__ WU,
                                          unsigned short* __restrict__ zimg) {
  __shared__ __align__(16) char bufA[67584];  // A hi/lo 64KB; reused as zt f32 [128][132]
  __shared__ __align__(16) char bufB[65536];
  int orig = blockIdx.x;
  int blk = (orig & 7) * 128 + (orig >> 3);  // XCD swizzle (1024 = 8*128)
  int h = blk & 3, mt = (blk >> 2) & 3, b = blk >> 4;
  int t = threadIdx.x, ln = t & 63, wv = t >> 6;
  int R0 = (wv >> 1) * 64, C0 = (wv & 1) * 64;

  // stage A = X2 tile [m=128][e=128] hi/lo, XOR-swizzled chunks
#pragma unroll
  for (int p = 0; p < 8; ++p) {
    int c = p * 256 + t, r = c >> 4, kc = c & 15;
    const float* src = X2 + ((size_t)(mt * 128 + r) * Bn + b) * Dn + kc * 8;
    float xs[8];
    *(float4*)xs = *(const float4*)src;
    *(float4*)(xs + 4) = *(const float4*)(src + 4);
    short8 hi, lo;
    split8(xs, hi, lo);
    int byte = r * 256 + ((kc ^ (r & 7)) * 16);
    *(short8*)(bufA + byte) = hi;
    *(short8*)(bufA + 32768 + byte) = lo;
  }
  // stage B = WU[h] as [n=d rows][k=e]
#pragma unroll
  for (int p = 0; p < 8; ++p) {
    int c = p * 256 + t, r = c >> 4, kc = c & 15;
    const float* src = WU + ((size_t)(h * Dn + r)) * Dn + kc * 8;
    float xs[8];
    *(float4*)xs = *(const float4*)src;
    *(float4*)(xs + 4) = *(const float4*)(src + 4);
    short8 hi, lo;
    split8(xs, hi, lo);
    int byte = r * 256 + ((kc ^ (r & 7)) * 16);
    *(short8*)(bufB + byte) = hi;
    *(short8*)(bufB + 32768 + byte) = lo;
  }
  __syncthreads();

  f32x4 acc[4][4];
  const f32x4 fz = {0.f, 0.f, 0.f, 0.f};
#pragma unroll
  for (int i = 0; i < 4; ++i)
#pragma unroll
    for (int j = 0; j < 4; ++j) acc[i][j] = fz;

#pragma unroll
  for (int ks = 0; ks < 4; ++ks) {
    short8 bhf[4], blf[4];
#pragma unroll
    for (int nr = 0; nr < 4; ++nr) {
      int r = C0 + nr * 16 + (ln & 15);
      int byte = r * 256 + (((ks * 4 + (ln >> 4)) ^ (r & 7)) * 16);
      bhf[nr] = *(const short8*)(bufB + byte);
      blf[nr] = *(const short8*)(bufB + 32768 + byte);
    }
#pragma unroll
    for (int mr = 0; mr < 4; ++mr) {
      int r = R0 + mr * 16 + (ln & 15);
      int byte = r * 256 + (((ks * 4 + (ln >> 4)) ^ (r & 7)) * 16);
      short8 ah = *(const short8*)(bufA + byte);
      short8 al = *(const short8*)(bufA + 32768 + byte);
#pragma unroll
      for (int nr = 0; nr < 4; ++nr) {
        acc[mr][nr] = __builtin_amdgcn_mfma_f32_16x16x32_bf16(ah, bhf[nr], acc[mr][nr], 0, 0, 0);
        acc[mr][nr] = __builtin_amdgcn_mfma_f32_16x16x32_bf16(ah, blf[nr], acc[mr][nr], 0, 0, 0);
        acc[mr][nr] = __builtin_amdgcn_mfma_f32_16x16x32_bf16(al, bhf[nr], acc[mr][nr], 0, 0, 0);
      }
    }
  }
  __syncthreads();
  // acc -> zt f32 [128 m][132] (pad) ; C layout: col=ln&15, row=(ln>>4)*4+j
  float* zt = (float*)bufA;
#pragma unroll
  for (int mr = 0; mr < 4; ++mr) {
    int rbase = R0 + mr * 16 + (ln >> 4) * 4;
#pragma unroll
    for (int nr = 0; nr < 4; ++nr) {
      int d = C0 + nr * 16 + (ln & 15);
#pragma unroll
      for (int j = 0; j < 4; ++j) zt[(rbase + j) * 132 + d] = acc[mr][nr][j];
    }
  }
  __syncthreads();
  // convert + store swizzle-ordered images
  size_t tbase = (size_t)((b * 4 + h) * 4 + mt) * 32768;
#pragma unroll
  for (int p = 0; p < 8; ++p) {
    int c = p * 256 + t, r = c >> 4, kc = c & 15;
    float xs[8];
    *(float4*)xs = *(const float4*)(zt + r * 132 + kc * 8);
    *(float4*)(xs + 4) = *(const float4*)(zt + r * 132 + kc * 8 + 4);
    short8 hi, lo;
    split8(xs, hi, lo);
    int csw = c ^ (r & 7);
    *(short8*)(zimg + tbase + (size_t)csw * 8) = hi;
    *(short8*)(zimg + tbase + 16384 + (size_t)csw * 8) = lo;
  }
}

// ---------------- k1: masked row/col maxes of S = X1 . Z^T (split MFMA) --
// grid: b*16 + h*4 + lt (XCD-swizzled). 4 waves, 64x64 wave tiles.
__global__ __launch_bounds__(256) void k1(const float* __restrict__ X1,
                                          const unsigned short* __restrict__ zimg,
                                          const int* __restrict__ raw1,
                                          const int* __restrict__ raw2,
                                          float* __restrict__ s1,
                                          float* __restrict__ s2p) {
  __shared__ __align__(16) char shA[65536];
  __shared__ __align__(16) char shB[65536];
  __shared__ float cmlds[2][512];
  __shared__ float rmx[4][64];
  __shared__ float m1f[128];
  __shared__ float m2f[512];

  int orig = blockIdx.x;
  int blk = (orig & 7) * 128 + (orig >> 3);
  int lt = blk & 3, h = (blk >> 2) & 3, b = blk >> 4;
  int bh = b * 4 + h;
  int t = threadIdx.x, ln = t & 63, wv = t >> 6;
  int R0 = (wv >> 1) * 64, C0 = (wv & 1) * 64;

  for (int i = t; i < 512; i += 256)
    m2f[i] = (raw2[(size_t)i * Bn + b] == 0) ? 1.0f : 0.0f;
  if (t < 128) m1f[t] = (raw1[(size_t)(lt * 128 + t) * Bn + b] == 0) ? 1.0f : 0.0f;
  for (int i = t; i < 1024; i += 256) ((float*)cmlds)[i] = -3.0e38f;

  // stage A from X1 (reg path: f32 -> hi/lo, swizzled ds_write)
#pragma unroll
  for (int p = 0; p < 8; ++p) {
    int c = p * 256 + t, r = c >> 4, kc = c & 15;
    const float* src = X1 + ((size_t)(lt * 128 + r) * Bn + b) * Dn + kc * 8;
    float xs[8];
    *(float4*)xs = *(const float4*)src;
    *(float4*)(xs + 4) = *(const float4*)(src + 4);
    short8 hi, lo;
    split8(xs, hi, lo);
    int byte = r * 256 + ((kc ^ (r & 7)) * 16);
    *(short8*)(shA + byte) = hi;
    *(short8*)(shA + 32768 + byte) = lo;
  }
  // stage B tile mt=0 via global_load_lds (images already swizzle-ordered)
  {
    size_t tb = (size_t)(bh * 4 + 0) * 32768;
#pragma unroll
    for (int p = 0; p < 8; ++p) {
      int cw = p * 256 + wv * 64;
      gll16(zimg + tb + (size_t)(cw + ln) * 8, shB + cw * 16);
      gll16(zimg + tb + 16384 + (size_t)(cw + ln) * 8, shB + 32768 + cw * 16);
    }
  }
  __syncthreads();

  // per-lane mask bitfields
  unsigned m1b = 0, m2b = 0;
#pragma unroll
  for (int mr = 0; mr < 4; ++mr)
#pragma unroll
    for (int j = 0; j < 4; ++j)
      if (m1f[R0 + mr * 16 + (ln >> 4) * 4 + j] != 0.0f) m1b |= 1u << (mr * 4 + j);
#pragma unroll
  for (int mt = 0; mt < 4; ++mt)
#pragma unroll
    for (int nr = 0; nr < 4; ++nr)
      if (m2f[mt * 128 + C0 + nr * 16 + (ln & 15)] != 0.0f) m2b |= 1u << (mt * 4 + nr);

  float rmrun[4][4];
#pragma unroll
  for (int i = 0; i < 4; ++i)
#pragma unroll
    for (int j = 0; j < 4; ++j) rmrun[i][j] = -3.0e38f;

  for (int mt = 0; mt < 4; ++mt) {
    if (mt > 0) __syncthreads();  // staging for this mt complete
    f32x4 acc[4][4];
    const f32x4 fz = {0.f, 0.f, 0.f, 0.f};
#pragma unroll
    for (int i = 0; i < 4; ++i)
#pragma unroll
      for (int j = 0; j < 4; ++j) acc[i][j] = fz;

#pragma unroll
    for (int ks = 0; ks < 4; ++ks) {
      short8 bhf[4], blf[4];
#pragma unroll
      for (int nr = 0; nr < 4; ++nr) {
        int r = C0 + nr * 16 + (ln & 15);
        int byte = r * 256 + (((ks * 4 + (ln >> 4)) ^ (r & 7)) * 16);
        bhf[nr] = *(const short8*)(shB + byte);
        blf[nr] = *(const short8*)(shB + 32768 + byte);
      }
#pragma unroll
      for (int mr = 0; mr < 4; ++mr) {
        int r = R0 + mr * 16 + (ln & 15);
        int byte = r * 256 + (((ks * 4 + (ln >> 4)) ^ (r & 7)) * 16);
        short8 ah = *(const short8*)(shA + byte);
        short8 al = *(const short8*)(shA + 32768 + byte);
#pragma unroll
        for (int nr = 0; nr < 4; ++nr) {
          acc[mr][nr] = __builtin_amdgcn_mfma_f32_16x16x32_bf16(ah, bhf[nr], acc[mr][nr], 0, 0, 0);
          acc[mr][nr] = __builtin_amdgcn_mfma_f32_16x16x32_bf16(ah, blf[nr], acc[mr][nr], 0, 0, 0);
          acc[mr][nr] = __builtin_amdgcn_mfma_f32_16x16x32_bf16(al, bhf[nr], acc[mr][nr], 0, 0, 0);
        }
      }
    }
    __syncthreads();  // all reads of shB done
    if (mt < 3) {     // prefetch next B tile; overlaps reductions below
      size_t tb = (size_t)(bh * 4 + mt + 1) * 32768;
#pragma unroll
      for (int p = 0; p < 8; ++p) {
        int cw = p * 256 + wv * 64;
        gll16(zimg + tb + (size_t)(cw + ln) * 8, shB + cw * 16);
        gll16(zimg + tb + 16384 + (size_t)(cw + ln) * 8, shB + 32768 + cw * 16);
      }
    }

    // row-max over this mt's cols (mask2), running across mt
#pragma unroll
    for (int mr = 0; mr < 4; ++mr)
#pragma unroll
      for (int j = 0; j < 4; ++j) {
        float v = -3.0e38f;
#pragma unroll
        for (int nr = 0; nr < 4; ++nr) {
          float s = acc[mr][nr][j];
          if ((m2b >> (mt * 4 + nr)) & 1) s -= 1.0e4f;
          v = fmaxf(v, s);
        }
        v = fmaxf(v, __shfl_xor(v, 1));
        v = fmaxf(v, __shfl_xor(v, 2));
        v = fmaxf(v, __shfl_xor(v, 4));
        v = fmaxf(v, __shfl_xor(v, 8));
        rmrun[mr][j] = fmaxf(rmrun[mr][j], v);
      }
    // col-max over this wave's rows (mask1) -> cmlds running
#pragma unroll
    for (int nr = 0; nr < 4; ++nr) {
      float v = -3.0e38f;
#pragma unroll
      for (int mr = 0; mr < 4; ++mr)
#pragma unroll
        for (int j = 0; j < 4; ++j) {
          float s = acc[mr][nr][j];
          if ((m1b >> (mr * 4 + j)) & 1) s -= 1.0e4f;
          v = fmaxf(v, s);
        }
      v = fmaxf(v, __shfl_xor(v, 16));
      v = fmaxf(v, __shfl_xor(v, 32));
      if (ln < 16) {
        float* p = &cmlds[wv >> 1][mt * 128 + C0 + nr * 16 + ln];
        *p = fmaxf(*p, v);
      }
    }
  }

  // epilogue: cross-wave row-max combine, write s1 (complete) and s2p (lt-partial)
  if ((ln & 15) == 0) {
#pragma unroll
    for (int mr = 0; mr < 4; ++mr)
#pragma unroll
      for (int j = 0; j < 4; ++j)
        rmx[wv][mr * 16 + (ln >> 4) * 4 + j] = rmrun[mr][j];
  }
  __syncthreads();
  if (t < 128) {
    int wa = (t >> 6) * 2, i = t & 63;
    s1[(size_t)bh * 512 + lt * 128 + t] = fmaxf(rmx[wa][i], rmx[wa + 1][i]);
  }
  for (int i = t; i < 512; i += 256)
    s2p[((size_t)bh * 4 + lt) * 512 + i] = fmaxf(cmlds[0][i], cmlds[1][i]);
}

// ---------------- k2: tanh -> softmax -> a out, readout r ----------------
__global__ __launch_bounds__(256) void k2(const float* __restrict__ s1,
                                          const float* __restrict__ s2p,
                                          const float* __restrict__ X1,
                                          const float* __restrict__ X2,
                                          float* __restrict__ out,
                                          float* __restrict__ rws) {
  int blk = blockIdx.x;  // 0..511
  int side = blk >> 8, bh = blk & 255;
  int b = bh >> 2;
  int t = threadIdx.x;
  __shared__ float a[512];
  __shared__ float red[256];

  for (int i = t; i < 512; i += 256) {
    float v;
    if (side == 0) {
      v = s1[(size_t)bh * 512 + i];
    } else {
      v = s2p[((size_t)bh * 4 + 0) * 512 + i];
#pragma unroll
      for (int l = 1; l < 4; ++l) v = fmaxf(v, s2p[((size_t)bh * 4 + l) * 512 + i]);
    }
    a[i] = tanhf(v);
  }
  __syncthreads();
  red[t] = fmaxf(a[t], a[t + 256]);
  __syncthreads();
  for (int s = 128; s > 0; s >>= 1) {
    if (t < s) red[t] = fmaxf(red[t], red[t + s]);
    __syncthreads();
  }
  float mx = red[0];
  __syncthreads();
  float e0 = expf(a[t] - mx), e1 = expf(a[t + 256] - mx);
  red[t] = e0 + e1;
  __syncthreads();
  for (int s = 128; s > 0; s >>= 1) {
    if (t < s) red[t] += red[t + s];
    __syncthreads();
  }
  float inv = 1.0f / red[0];
  __syncthreads();
  a[t] = e0 * inv;
  a[t + 256] = e1 * inv;
  __syncthreads();

  int aoff = (side == 0 ? 16384 : 147456) + bh * 512;
  out[aoff + t] = a[t];
  out[aoff + t + 256] = a[t + 256];

  const float* X = (side == 0) ? X1 : X2;
  int d = t & 127, part = t >> 7;
  float acc = 0.0f;
  for (int l = part; l < 512; l += 2) acc += a[l] * X[((size_t)l * Bn + b) * Dn + d];
  __syncthreads();
  red[t] = acc;
  __syncthreads();
  if (t < 128) rws[side * 32768 + bh * 128 + t] = red[t] + red[t + 128];
}

// ---------------- K3: combine hops ----------------
__global__ __launch_bounds__(128) void k3(const float* __restrict__ rws,
                                          const float* __restrict__ Wipm,
                                          float* __restrict__ out) {
  int b = blockIdx.x, t = threadIdx.x;  // t = d
  __shared__ float r2l[4][128];
  __shared__ float tsum[2][4];
  float r1h[4], r2h[4];
#pragma unroll
  for (int h = 0; h < 4; ++h) {
    r1h[h] = rws[(b * 4 + h) * 128 + t];
    r2h[h] = rws[32768 + (b * 4 + h) * 128 + t];
    r2l[h][t] = r2h[h];
  }
  __syncthreads();
  float p[4] = {0, 0, 0, 0};
  for (int e = 0; e < 128; ++e) {
    float w = Wipm[t * 128 + e];
#pragma unroll
    for (int h = 0; h < 4; ++h) p[h] += w * r2l[h][e];
  }
#pragma unroll
  for (int h = 0; h < 4; ++h) p[h] *= r1h[h];
#pragma unroll
  for (int off = 1; off < 64; off <<= 1)
#pragma unroll
    for (int h = 0; h < 4; ++h) p[h] += __shfl_xor(p[h], off);
  if ((t & 63) == 0)
#pragma unroll
    for (int h = 0; h < 4; ++h) tsum[t >> 6][h] = p[h];
  __syncthreads();
  float ad[4], mx = -3.0e38f;
#pragma unroll
  for (int h = 0; h < 4; ++h) {
    float v = tanhf(tsum[0][h] + tsum[1][h]);
    ad[h] = v;
    mx = fmaxf(mx, v);
  }
  float s = 0.0f;
#pragma unroll
  for (int h = 0; h < 4; ++h) { ad[h] = expf(ad[h] - mx); s += ad[h]; }
  float inv = 1.0f / s;
#pragma unroll
  for (int h = 0; h < 4; ++h) ad[h] *= inv;
  if (t < 4) out[278528 + b * 4 + t] = ad[t];
  float f1 = 0.0f, f2 = 0.0f;
#pragma unroll
  for (int h = 0; h < 4; ++h) { f1 += ad[h] * r1h[h]; f2 += ad[h] * r2h[h]; }
  out[b * 128 + t] = f1;
  out[8192 + b * 128 + t] = f2;
}

extern "C" void kernel_launch(void* const* d_in, const int* in_sizes, int n_in,
                              void* d_out, int out_size, void* d_ws,
                              size_t ws_size, hipStream_t stream) {
  (void)in_sizes; (void)n_in; (void)out_size; (void)ws_size;
  const float* x1 = (const float*)d_in[0];
  const float* x2 = (const float*)d_in[1];
  const int* raw1 = (const int*)d_in[2];
  const int* raw2 = (const int*)d_in[3];
  const float* wu = (const float*)d_in[4];
  const float* wipm = (const float*)d_in[5];
  float* out = (float*)d_out;
  // ws layout: zimg 64 MiB (1024 tiles * 2 comp * 16384 ushort), then f32 arrays
  unsigned short* zimg = (unsigned short*)d_ws;
  float* s1 = (float*)((char*)d_ws + 67108864);  // 131072 f32
  float* s2p = s1 + 131072;                      // 524288 f32
  float* rws = s2p + 524288;                     // 65536 f32

  kz<<<1024, 256, 0, stream>>>(x2, wu, zimg);
  k1<<<1024, 256, 0, stream>>>(x1, zimg, raw1, raw2, s1, s2p);
  k2<<<512, 256, 0, stream>>>(s1, s2p, x1, x2, out, rws);
  k3<<<64, 128, 0, stream>>>(rws, wipm, out);
}

// Round 3
// 166.761 us; speedup vs baseline: 2.4090x; 1.1586x over previous
//
#include <hip/hip_runtime.h>

#define Bn 64
#define Dn 128
#define Ln 512

typedef __attribute__((ext_vector_type(8))) short short8;
typedef __attribute__((ext_vector_type(4))) float f32x4;

// truncating bf16 split: x ~= hi + lo, |err| ~ 2^-16 rel (3-term MFMA)
__device__ __forceinline__ void split8(const float* xs, short8& hi, short8& lo) {
#pragma unroll
  for (int j = 0; j < 8; ++j) {
    unsigned int u = __float_as_uint(xs[j]);
    float l = xs[j] - __uint_as_float(u & 0xFFFF0000u);
    hi[j] = (short)(u >> 16);
    lo[j] = (short)(__float_as_uint(l) >> 16);
  }
}
__device__ __forceinline__ void gll16(const void* g, void* l) {
  __builtin_amdgcn_global_load_lds(
      (const __attribute__((address_space(1))) void*)g,
      (__attribute__((address_space(3))) void*)l, 16, 0, 0);
}

// ---- kz: Z[bh][m][d] = sum_e X2[m,b,e] WU[h,d,e]; split-bf16 chunk-swizzled
// images. grid 1024: blk = b*16 + mt*4 + h. No input staging; LDS = zt only.
__global__ __launch_bounds__(256, 2) void kz(const float* __restrict__ X2,
                                             const float* __restrict__ WU,
                                             unsigned short* __restrict__ zimg) {
  __shared__ __align__(16) float zt[128 * 132];  // 67584 B -> 2 blocks/CU
  int orig = blockIdx.x;
  int blk = (orig & 7) * 128 + (orig >> 3);  // XCD swizzle
  int h = blk & 3, mt = (blk >> 2) & 3, b = blk >> 4;
  int t = threadIdx.x, ln = t & 63, wv = t >> 6;
  int R0 = (wv >> 1) * 64, C0 = (wv & 1) * 64;
  int eo = (ln >> 4) * 8;

  f32x4 acc[4][4];
  const f32x4 fz = {0.f, 0.f, 0.f, 0.f};
#pragma unroll
  for (int i = 0; i < 4; ++i)
#pragma unroll
    for (int j = 0; j < 4; ++j) acc[i][j] = fz;

#pragma unroll
  for (int ks = 0; ks < 4; ++ks) {
    short8 ahf[4], alf[4], bhf[4], blf[4];
#pragma unroll
    for (int mr = 0; mr < 4; ++mr) {
      int m = mt * 128 + R0 + mr * 16 + (ln & 15);
      const float* src = X2 + ((size_t)m * Bn + b) * Dn + ks * 32 + eo;
      float xs[8];
      *(float4*)xs = *(const float4*)src;
      *(float4*)(xs + 4) = *(const float4*)(src + 4);
      split8(xs, ahf[mr], alf[mr]);
    }
#pragma unroll
    for (int nr = 0; nr < 4; ++nr) {
      int d = C0 + nr * 16 + (ln & 15);
      const float* src = WU + ((size_t)(h * Dn + d)) * Dn + ks * 32 + eo;
      float xs[8];
      *(float4*)xs = *(const float4*)src;
      *(float4*)(xs + 4) = *(const float4*)(src + 4);
      split8(xs, bhf[nr], blf[nr]);
    }
#pragma unroll
    for (int mr = 0; mr < 4; ++mr)
#pragma unroll
      for (int nr = 0; nr < 4; ++nr) {
        acc[mr][nr] = __builtin_amdgcn_mfma_f32_16x16x32_bf16(ahf[mr], bhf[nr], acc[mr][nr], 0, 0, 0);
        acc[mr][nr] = __builtin_amdgcn_mfma_f32_16x16x32_bf16(ahf[mr], blf[nr], acc[mr][nr], 0, 0, 0);
        acc[mr][nr] = __builtin_amdgcn_mfma_f32_16x16x32_bf16(alf[mr], bhf[nr], acc[mr][nr], 0, 0, 0);
      }
  }
  // transpose via LDS: frag layout -> row-major rows of Z
#pragma unroll
  for (int mr = 0; mr < 4; ++mr) {
    int rb = R0 + mr * 16 + (ln >> 4) * 4;
#pragma unroll
    for (int nr = 0; nr < 4; ++nr) {
      int d = C0 + nr * 16 + (ln & 15);
#pragma unroll
      for (int j = 0; j < 4; ++j) zt[(rb + j) * 132 + d] = acc[mr][nr][j];
    }
  }
  __syncthreads();
  size_t tbase = (size_t)((b * 4 + h) * 4 + mt) * 32768;
#pragma unroll
  for (int p = 0; p < 8; ++p) {
    int c = p * 256 + t, r = c >> 4, kc = c & 15;
    float xs[8];
    *(float4*)xs = *(const float4*)(zt + r * 132 + kc * 8);
    *(float4*)(xs + 4) = *(const float4*)(zt + r * 132 + kc * 8 + 4);
    short8 hi, lo;
    split8(xs, hi, lo);
    int csw = r * 16 + (kc ^ (r & 7));
    *(short8*)(zimg + tbase + (size_t)csw * 8) = hi;
    *(short8*)(zimg + tbase + 16384 + (size_t)csw * 8) = lo;
  }
}

// ---- k1: masked row/col maxes of S = X1 . Z^T. grid 1024: b*16+h*4+lt.
// A-frags in regs (global-loaded); B double-buffered 64-col tiles in LDS.
__global__ __launch_bounds__(256, 2) void k1(const float* __restrict__ X1,
                                             const unsigned short* __restrict__ zimg,
                                             const int* __restrict__ raw1,
                                             const int* __restrict__ raw2,
                                             float* __restrict__ s1,
                                             float* __restrict__ s2p) {
  __shared__ __align__(16) char shB[65536];  // 2 x (hi 16K | lo 16K)
  __shared__ float cmlds[2][512];
  __shared__ float rmx[4][64];
  __shared__ float m1f[128];
  __shared__ float m2f[512];

  int orig = blockIdx.x;
  int blk = (orig & 7) * 128 + (orig >> 3);
  int lt = blk & 3, h = (blk >> 2) & 3, b = blk >> 4;
  int bh = b * 4 + h;
  int t = threadIdx.x, ln = t & 63, wv = t >> 6;
  int R0 = (wv >> 1) * 64, C0 = (wv & 1) * 32;

  for (int i = t; i < 512; i += 256)
    m2f[i] = (raw2[(size_t)i * Bn + b] == 0) ? 1.0f : 0.0f;
  if (t < 128) m1f[t] = (raw1[(size_t)(lt * 128 + t) * Bn + b] == 0) ? 1.0f : 0.0f;
  for (int i = t; i < 1024; i += 256) ((float*)cmlds)[i] = -3.0e38f;

#define STAGE(bb, mt_)                                                          \
  {                                                                             \
    int mtz = (mt_) >> 1, half = (mt_) & 1;                                     \
    size_t tb = (size_t)(bh * 4 + mtz) * 32768 + (size_t)half * 8192;           \
    _Pragma("unroll") for (int p = 0; p < 4; ++p) {                             \
      int cw = wv * 256 + p * 64;                                               \
      gll16(zimg + tb + (size_t)(cw + ln) * 8, shB + (bb)*32768 + cw * 16);     \
      gll16(zimg + tb + 16384 + (size_t)(cw + ln) * 8,                          \
            shB + (bb)*32768 + 16384 + cw * 16);                                \
    }                                                                           \
  }

  STAGE(0, 0);  // B tile 0 in flight during A-frag load

  // A-fragments from global (X1 rows are k-contiguous), kept in registers
  short8 ahf[4][4], alf[4][4];
  {
    int eo = (ln >> 4) * 8;
#pragma unroll
    for (int mr = 0; mr < 4; ++mr) {
      const float* rsrc =
          X1 + ((size_t)(lt * 128 + R0 + mr * 16 + (ln & 15)) * Bn + b) * Dn + eo;
#pragma unroll
      for (int ks = 0; ks < 4; ++ks) {
        float xs[8];
        *(float4*)xs = *(const float4*)(rsrc + ks * 32);
        *(float4*)(xs + 4) = *(const float4*)(rsrc + ks * 32 + 4);
        split8(xs, ahf[mr][ks], alf[mr][ks]);
      }
    }
  }
  __syncthreads();  // drains STAGE(0) + mask/cmlds writes

  // per-lane mask bitfields
  unsigned m1b = 0, m2b = 0;
#pragma unroll
  for (int mr = 0; mr < 4; ++mr)
#pragma unroll
    for (int j = 0; j < 4; ++j)
      if (m1f[R0 + mr * 16 + (ln >> 4) * 4 + j] != 0.0f) m1b |= 1u << (mr * 4 + j);
#pragma unroll
  for (int mt = 0; mt < 8; ++mt)
#pragma unroll
    for (int nr = 0; nr < 2; ++nr)
      if (m2f[mt * 64 + C0 + nr * 16 + (ln & 15)] != 0.0f) m2b |= 1u << (mt * 2 + nr);

  float rmrun[4][4];
#pragma unroll
  for (int i = 0; i < 4; ++i)
#pragma unroll
    for (int j = 0; j < 4; ++j) rmrun[i][j] = -3.0e38f;

  int cur = 0;
  for (int mt = 0; mt < 8; ++mt) {
    if (mt < 7) STAGE(cur ^ 1, mt + 1);  // issue-early; buffer freed at prev barrier

    f32x4 acc[4][2];
    const f32x4 fz = {0.f, 0.f, 0.f, 0.f};
#pragma unroll
    for (int i = 0; i < 4; ++i) {
      acc[i][0] = fz;
      acc[i][1] = fz;
    }
#pragma unroll
    for (int ks = 0; ks < 4; ++ks) {
      short8 bhf[2], blf[2];
#pragma unroll
      for (int nr = 0; nr < 2; ++nr) {
        int rr = C0 + nr * 16 + (ln & 15);
        int by = rr * 256 + (((ks * 4 + (ln >> 4)) ^ (rr & 7)) * 16);
        bhf[nr] = *(const short8*)(shB + cur * 32768 + by);
        blf[nr] = *(const short8*)(shB + cur * 32768 + 16384 + by);
      }
#pragma unroll
      for (int mr = 0; mr < 4; ++mr)
#pragma unroll
        for (int nr = 0; nr < 2; ++nr) {
          acc[mr][nr] = __builtin_amdgcn_mfma_f32_16x16x32_bf16(ahf[mr][ks], bhf[nr], acc[mr][nr], 0, 0, 0);
          acc[mr][nr] = __builtin_amdgcn_mfma_f32_16x16x32_bf16(ahf[mr][ks], blf[nr], acc[mr][nr], 0, 0, 0);
          acc[mr][nr] = __builtin_amdgcn_mfma_f32_16x16x32_bf16(alf[mr][ks], bhf[nr], acc[mr][nr], 0, 0, 0);
        }
    }

    // row-max (mask2) running across mt
#pragma unroll
    for (int mr = 0; mr < 4; ++mr)
#pragma unroll
      for (int j = 0; j < 4; ++j) {
        float v = -3.0e38f;
#pragma unroll
        for (int nr = 0; nr < 2; ++nr) {
          float s = acc[mr][nr][j];
          if ((m2b >> (mt * 2 + nr)) & 1) s -= 1.0e4f;
          v = fmaxf(v, s);
        }
        v = fmaxf(v, __shfl_xor(v, 1));
        v = fmaxf(v, __shfl_xor(v, 2));
        v = fmaxf(v, __shfl_xor(v, 4));
        v = fmaxf(v, __shfl_xor(v, 8));
        rmrun[mr][j] = fmaxf(rmrun[mr][j], v);
      }
    // col-max (mask1) -> cmlds running
#pragma unroll
    for (int nr = 0; nr < 2; ++nr) {
      float v = -3.0e38f;
#pragma unroll
      for (int mr = 0; mr < 4; ++mr)
#pragma unroll
        for (int j = 0; j < 4; ++j) {
          float s = acc[mr][nr][j];
          if ((m1b >> (mr * 4 + j)) & 1) s -= 1.0e4f;
          v = fmaxf(v, s);
        }
      v = fmaxf(v, __shfl_xor(v, 16));
      v = fmaxf(v, __shfl_xor(v, 32));
      if (ln < 16) {
        float* p = &cmlds[wv >> 1][mt * 64 + C0 + nr * 16 + ln];
        *p = fmaxf(*p, v);
      }
    }
    __syncthreads();  // drains this iter's STAGE; separates reads from overwrite
    cur ^= 1;
  }

  // epilogue
  if ((ln & 15) == 0) {
#pragma unroll
    for (int mr = 0; mr < 4; ++mr)
#pragma unroll
      for (int j = 0; j < 4; ++j)
        rmx[wv][mr * 16 + (ln >> 4) * 4 + j] = rmrun[mr][j];
  }
  __syncthreads();
  if (t < 128) {
    int wa = (t >> 6) * 2, i = t & 63;
    s1[(size_t)bh * 512 + lt * 128 + t] = fmaxf(rmx[wa][i], rmx[wa + 1][i]);
  }
  for (int i = t; i < 512; i += 256)
    s2p[((size_t)bh * 4 + lt) * 512 + i] = fmaxf(cmlds[0][i], cmlds[1][i]);
#undef STAGE
}

// ---- k2: tanh -> softmax -> a out, vectorized readout r ----
__global__ __launch_bounds__(256) void k2(const float* __restrict__ s1,
                                          const float* __restrict__ s2p,
                                          const float* __restrict__ X1,
                                          const float* __restrict__ X2,
                                          float* __restrict__ out,
                                          float* __restrict__ rws) {
  int blk = blockIdx.x;  // 0..511
  int side = blk >> 8, bh = blk & 255;
  int b = bh >> 2;
  int t = threadIdx.x;
  __shared__ float a[512];
  __shared__ float red[256];
  __shared__ f32x4 redv[256];

  for (int i = t; i < 512; i += 256) {
    float v;
    if (side == 0) {
      v = s1[(size_t)bh * 512 + i];
    } else {
      v = s2p[((size_t)bh * 4 + 0) * 512 + i];
#pragma unroll
      for (int l = 1; l < 4; ++l) v = fmaxf(v, s2p[((size_t)bh * 4 + l) * 512 + i]);
    }
    a[i] = tanhf(v);
  }
  __syncthreads();
  red[t] = fmaxf(a[t], a[t + 256]);
  __syncthreads();
  for (int s = 128; s > 0; s >>= 1) {
    if (t < s) red[t] = fmaxf(red[t], red[t + s]);
    __syncthreads();
  }
  float mx = red[0];
  __syncthreads();
  float e0 = expf(a[t] - mx), e1 = expf(a[t + 256] - mx);
  red[t] = e0 + e1;
  __syncthreads();
  for (int s = 128; s > 0; s >>= 1) {
    if (t < s) red[t] += red[t + s];
    __syncthreads();
  }
  float inv = 1.0f / red[0];
  __syncthreads();
  a[t] = e0 * inv;
  a[t + 256] = e1 * inv;
  __syncthreads();

  int aoff = (side == 0 ? 16384 : 147456) + bh * 512;
  out[aoff + t] = a[t];
  out[aoff + t + 256] = a[t + 256];

  // r[d] = sum_l a[l] * X[l][b][d], float4 over d
  const float4* X4 = (const float4*)((side == 0) ? X1 : X2);
  int q = t & 31, lg = t >> 5;
  f32x4 acc = {0.f, 0.f, 0.f, 0.f};
  for (int l = lg; l < 512; l += 8) {
    float4 v = X4[((size_t)l * Bn + b) * 32 + q];
    float w = a[l];
    acc[0] += w * v.x;
    acc[1] += w * v.y;
    acc[2] += w * v.z;
    acc[3] += w * v.w;
  }
  redv[t] = acc;
  __syncthreads();
  if (t < 128) {
    float s = 0.0f;
#pragma unroll
    for (int g = 0; g < 8; ++g) s += ((const float*)&redv[g * 32 + (t >> 2)])[t & 3];
    rws[side * 32768 + bh * 128 + t] = s;
  }
}

// ---- k3: combine hops ----
__global__ __launch_bounds__(128) void k3(const float* __restrict__ rws,
                                          const float* __restrict__ Wipm,
                                          float* __restrict__ out) {
  int b = blockIdx.x, t = threadIdx.x;  // t = d
  __shared__ float r2l[4][128];
  __shared__ float tsum[2][4];
  float r1h[4], r2h[4];
#pragma unroll
  for (int h = 0; h < 4; ++h) {
    r1h[h] = rws[(b * 4 + h) * 128 + t];
    r2h[h] = rws[32768 + (b * 4 + h) * 128 + t];
    r2l[h][t] = r2h[h];
  }
  __syncthreads();
  float p[4] = {0, 0, 0, 0};
  for (int e = 0; e < 128; ++e) {
    float w = Wipm[t * 128 + e];
#pragma unroll
    for (int h = 0; h < 4; ++h) p[h] += w * r2l[h][e];
  }
#pragma unroll
  for (int h = 0; h < 4; ++h) p[h] *= r1h[h];
#pragma unroll
  for (int off = 1; off < 64; off <<= 1)
#pragma unroll
    for (int h = 0; h < 4; ++h) p[h] += __shfl_xor(p[h], off);
  if ((t & 63) == 0)
#pragma unroll
    for (int h = 0; h < 4; ++h) tsum[t >> 6][h] = p[h];
  __syncthreads();
  float ad[4], mx = -3.0e38f;
#pragma unroll
  for (int h = 0; h < 4; ++h) {
    float v = tanhf(tsum[0][h] + tsum[1][h]);
    ad[h] = v;
    mx = fmaxf(mx, v);
  }
  float s = 0.0f;
#pragma unroll
  for (int h = 0; h < 4; ++h) { ad[h] = expf(ad[h] - mx); s += ad[h]; }
  float inv = 1.0f / s;
#pragma unroll
  for (int h = 0; h < 4; ++h) ad[h] *= inv;
  if (t < 4) out[278528 + b * 4 + t] = ad[t];
  float f1 = 0.0f, f2 = 0.0f;
#pragma unroll
  for (int h = 0; h < 4; ++h) { f1 += ad[h] * r1h[h]; f2 += ad[h] * r2h[h]; }
  out[b * 128 + t] = f1;
  out[8192 + b * 128 + t] = f2;
}

extern "C" void kernel_launch(void* const* d_in, const int* in_sizes, int n_in,
                              void* d_out, int out_size, void* d_ws,
                              size_t ws_size, hipStream_t stream) {
  (void)in_sizes; (void)n_in; (void)out_size; (void)ws_size;
  const float* x1 = (const float*)d_in[0];
  const float* x2 = (const float*)d_in[1];
  const int* raw1 = (const int*)d_in[2];
  const int* raw2 = (const int*)d_in[3];
  const float* wu = (const float*)d_in[4];
  const float* wipm = (const float*)d_in[5];
  float* out = (float*)d_out;
  unsigned short* zimg = (unsigned short*)d_ws;   // 64 MiB
  float* s1 = (float*)((char*)d_ws + 67108864);   // 131072 f32
  float* s2p = s1 + 131072;                       // 524288 f32
  float* rws = s2p + 524288;                      // 65536 f32

  kz<<<1024, 256, 0, stream>>>(x2, wu, zimg);
  k1<<<1024, 256, 0, stream>>>(x1, zimg, raw1, raw2, s1, s2p);
  k2<<<512, 256, 0, stream>>>(s1, s2p, x1, x2, out, rws);
  k3<<<64, 128, 0, stream>>>(rws, wipm, out);
}

// Round 4
// 130.982 us; speedup vs baseline: 3.0670x; 1.2732x over previous
//
#include <hip/hip_runtime.h>

#define Bn 64
#define Dn 128
#define Ln 512

typedef __attribute__((ext_vector_type(8))) short short8;
typedef __attribute__((ext_vector_type(4))) float f32x4;

// truncating bf16 split: x ~= hi + lo
__device__ __forceinline__ void split8(const float* xs, short8& hi, short8& lo) {
#pragma unroll
  for (int j = 0; j < 8; ++j) {
    unsigned int u = __float_as_uint(xs[j]);
    float l = xs[j] - __uint_as_float(u & 0xFFFF0000u);
    hi[j] = (short)(u >> 16);
    lo[j] = (short)(__float_as_uint(l) >> 16);
  }
}

// ---- kz: Z[bh][m][d] = sum_e X2[m,b,e] WU[h,d,e]; writes fragment-ordered
// bf16 hi/lo images: unit(bh, mgrp=m>>4, ks, comp) of 1KB; lane ln holds
// Z[mgrp*16+(ln&15)][ks*32+(ln>>4)*8 .. +8]. grid 1024: blk = b*16+mt*4+h.
__global__ __launch_bounds__(256, 2) void kz(const float* __restrict__ X2,
                                             const float* __restrict__ WU,
                                             unsigned short* __restrict__ zimg) {
  __shared__ __align__(16) float zt[128 * 132];
  int orig = blockIdx.x;
  int blk = (orig & 7) * 128 + (orig >> 3);  // XCD swizzle
  int h = blk & 3, mt = (blk >> 2) & 3, b = blk >> 4;
  int t = threadIdx.x, ln = t & 63, wv = t >> 6;
  int R0 = (wv >> 1) * 64, C0 = (wv & 1) * 64;
  int eo = (ln >> 4) * 8;

  f32x4 acc[4][4];
  const f32x4 fz = {0.f, 0.f, 0.f, 0.f};
#pragma unroll
  for (int i = 0; i < 4; ++i)
#pragma unroll
    for (int j = 0; j < 4; ++j) acc[i][j] = fz;

#pragma unroll
  for (int ks = 0; ks < 4; ++ks) {
    short8 ahf[4], alf[4], bhf[4], blf[4];
#pragma unroll
    for (int mr = 0; mr < 4; ++mr) {
      int m = mt * 128 + R0 + mr * 16 + (ln & 15);
      const float* src = X2 + ((size_t)m * Bn + b) * Dn + ks * 32 + eo;
      float xs[8];
      *(float4*)xs = *(const float4*)src;
      *(float4*)(xs + 4) = *(const float4*)(src + 4);
      split8(xs, ahf[mr], alf[mr]);
    }
#pragma unroll
    for (int nr = 0; nr < 4; ++nr) {
      int d = C0 + nr * 16 + (ln & 15);
      const float* src = WU + ((size_t)(h * Dn + d)) * Dn + ks * 32 + eo;
      float xs[8];
      *(float4*)xs = *(const float4*)src;
      *(float4*)(xs + 4) = *(const float4*)(src + 4);
      split8(xs, bhf[nr], blf[nr]);
    }
#pragma unroll
    for (int mr = 0; mr < 4; ++mr)
#pragma unroll
      for (int nr = 0; nr < 4; ++nr) {
        acc[mr][nr] = __builtin_amdgcn_mfma_f32_16x16x32_bf16(ahf[mr], bhf[nr], acc[mr][nr], 0, 0, 0);
        acc[mr][nr] = __builtin_amdgcn_mfma_f32_16x16x32_bf16(ahf[mr], blf[nr], acc[mr][nr], 0, 0, 0);
        acc[mr][nr] = __builtin_amdgcn_mfma_f32_16x16x32_bf16(alf[mr], bhf[nr], acc[mr][nr], 0, 0, 0);
      }
  }
  // transpose via LDS: frag layout -> row-major rows of Z
#pragma unroll
  for (int mr = 0; mr < 4; ++mr) {
    int rb = R0 + mr * 16 + (ln >> 4) * 4;
#pragma unroll
    for (int nr = 0; nr < 4; ++nr) {
      int d = C0 + nr * 16 + (ln & 15);
#pragma unroll
      for (int j = 0; j < 4; ++j) zt[(rb + j) * 132 + d] = acc[mr][nr][j];
    }
  }
  __syncthreads();
  int bh = b * 4 + h;
#pragma unroll
  for (int p = 0; p < 8; ++p) {
    int u = p * 4 + (t >> 6);  // 0..31 : (mgrp_local = u>>2, ks = u&3)
    int r = (u >> 2) * 16 + (ln & 15);
    int d = (u & 3) * 32 + (ln >> 4) * 8;
    float xs[8];
    *(float4*)xs = *(const float4*)(zt + r * 132 + d);
    *(float4*)(xs + 4) = *(const float4*)(zt + r * 132 + d + 4);
    short8 hi, lo;
    split8(xs, hi, lo);
    size_t ub = ((((size_t)bh * 32 + mt * 8 + (u >> 2)) * 4 + (u & 3)) * 2) * 512 + (size_t)ln * 8;
    *(short8*)(zimg + ub) = hi;
    *(short8*)(zimg + ub + 512) = lo;
  }
}

// ---- k1: masked row/col maxes of S = X1 . Z^T. grid 1024: b*16+h*4+lt.
// Barrier-free main loop: A resident in regs, B streamed global->regs.
__global__ __launch_bounds__(256, 2) void k1(const float* __restrict__ X1,
                                             const unsigned short* __restrict__ zimg,
                                             const int* __restrict__ raw1,
                                             const int* __restrict__ raw2,
                                             float* __restrict__ s1pp,
                                             float* __restrict__ s2pp) {
  __shared__ float m1f[128];
  __shared__ float m2f[512];
  __shared__ float cmbuf[2][512];  // [rg][col] colmax partials

  int orig = blockIdx.x;
  int blk = (orig & 7) * 128 + (orig >> 3);
  int lt = blk & 3, h = (blk >> 2) & 3, b = blk >> 4;
  int bh = b * 4 + h;
  int t = threadIdx.x, ln = t & 63, wv = t >> 6;
  int rg = wv >> 1, cb = wv & 1;
  int R0 = rg * 64;

  for (int i = t; i < 512; i += 256) m2f[i] = (raw2[(size_t)i * Bn + b] == 0) ? 1.0e4f : 0.0f;
  if (t < 128) m1f[t] = (raw1[(size_t)(lt * 128 + t) * Bn + b] == 0) ? 1.0e4f : 0.0f;

  // A resident: rows lt*128 + R0 + mr*16 + (ln&15), k = ks*32 + (ln>>4)*8
  short8 ahf[4][4], alf[4][4];
  {
    int eo = (ln >> 4) * 8;
#pragma unroll
    for (int mr = 0; mr < 4; ++mr) {
      const float* rsrc =
          X1 + ((size_t)(lt * 128 + R0 + mr * 16 + (ln & 15)) * Bn + b) * Dn + eo;
#pragma unroll
      for (int ks = 0; ks < 4; ++ks) {
        float xs[8];
        *(float4*)xs = *(const float4*)(rsrc + ks * 32);
        *(float4*)(xs + 4) = *(const float4*)(rsrc + ks * 32 + 4);
        split8(xs, ahf[mr][ks], alf[mr][ks]);
      }
    }
  }
  __syncthreads();  // masks ready

  float msub1[4][4];
#pragma unroll
  for (int mr = 0; mr < 4; ++mr)
#pragma unroll
    for (int j = 0; j < 4; ++j) msub1[mr][j] = m1f[R0 + mr * 16 + (ln >> 4) * 4 + j];
  unsigned m2b = 0;
#pragma unroll
  for (int ph = 0; ph < 8; ++ph)
#pragma unroll
    for (int nr = 0; nr < 2; ++nr)
      if (m2f[cb * 256 + ph * 32 + nr * 16 + (ln & 15)] != 0.0f) m2b |= 1u << (ph * 2 + nr);

  float rmrun[4][4];
#pragma unroll
  for (int i = 0; i < 4; ++i)
#pragma unroll
    for (int j = 0; j < 4; ++j) rmrun[i][j] = -3.0e38f;

  const f32x4 fz = {0.f, 0.f, 0.f, 0.f};
  for (int ph = 0; ph < 8; ++ph) {  // cols = cb*256 + ph*32
    int cg = cb * 16 + ph * 2;
    f32x4 acc[4][2];
#pragma unroll
    for (int i = 0; i < 4; ++i) {
      acc[i][0] = fz;
      acc[i][1] = fz;
    }
#pragma unroll
    for (int ks = 0; ks < 4; ++ks) {
      const unsigned short* ubase =
          zimg + ((((size_t)bh * 32 + cg) * 4 + ks) * 2) * 512 + (size_t)ln * 8;
      short8 b0h = *(const short8*)ubase;
      short8 b0l = *(const short8*)(ubase + 512);
      short8 b1h = *(const short8*)(ubase + 4096);
      short8 b1l = *(const short8*)(ubase + 4608);
#pragma unroll
      for (int mr = 0; mr < 4; ++mr) {
        acc[mr][0] = __builtin_amdgcn_mfma_f32_16x16x32_bf16(ahf[mr][ks], b0h, acc[mr][0], 0, 0, 0);
        acc[mr][0] = __builtin_amdgcn_mfma_f32_16x16x32_bf16(ahf[mr][ks], b0l, acc[mr][0], 0, 0, 0);
        acc[mr][0] = __builtin_amdgcn_mfma_f32_16x16x32_bf16(alf[mr][ks], b0h, acc[mr][0], 0, 0, 0);
        acc[mr][1] = __builtin_amdgcn_mfma_f32_16x16x32_bf16(ahf[mr][ks], b1h, acc[mr][1], 0, 0, 0);
        acc[mr][1] = __builtin_amdgcn_mfma_f32_16x16x32_bf16(ahf[mr][ks], b1l, acc[mr][1], 0, 0, 0);
        acc[mr][1] = __builtin_amdgcn_mfma_f32_16x16x32_bf16(alf[mr][ks], b1h, acc[mr][1], 0, 0, 0);
      }
    }
    // masked reductions
    float ms0 = ((m2b >> (ph * 2)) & 1) ? 1.0e4f : 0.0f;
    float ms1 = ((m2b >> (ph * 2 + 1)) & 1) ? 1.0e4f : 0.0f;
#pragma unroll
    for (int mr = 0; mr < 4; ++mr)
#pragma unroll
      for (int j = 0; j < 4; ++j) {
        float c = fmaxf(acc[mr][0][j] - ms0, acc[mr][1][j] - ms1);
        rmrun[mr][j] = fmaxf(rmrun[mr][j], c);
      }
#pragma unroll
    for (int nr = 0; nr < 2; ++nr) {
      float v = -3.0e38f;
#pragma unroll
      for (int mr = 0; mr < 4; ++mr)
#pragma unroll
        for (int j = 0; j < 4; ++j) v = fmaxf(v, acc[mr][nr][j] - msub1[mr][j]);
      v = fmaxf(v, __shfl_xor(v, 16));
      v = fmaxf(v, __shfl_xor(v, 32));
      if (ln < 16) cmbuf[rg][cb * 256 + ph * 32 + nr * 16 + ln] = v;
    }
  }

  // epilogue: rowmax cross-lane + writes
#pragma unroll
  for (int off = 1; off < 16; off <<= 1)
#pragma unroll
    for (int mr = 0; mr < 4; ++mr)
#pragma unroll
      for (int j = 0; j < 4; ++j)
        rmrun[mr][j] = fmaxf(rmrun[mr][j], __shfl_xor(rmrun[mr][j], off));
  if ((ln & 15) == 0) {
    float* dst = s1pp + (((size_t)bh * 4 + lt) * 2 + cb) * 128;
#pragma unroll
    for (int mr = 0; mr < 4; ++mr)
#pragma unroll
      for (int j = 0; j < 4; ++j) dst[R0 + mr * 16 + (ln >> 4) * 4 + j] = rmrun[mr][j];
  }
  __syncthreads();
  for (int i = t; i < 1024; i += 256) {
    int rgi = i >> 9, col = i & 511;
    s2pp[(((size_t)bh * 4 + lt) * 2 + rgi) * 512 + col] = cmbuf[rgi][col];
  }
}

// ---- k2: per (side,b): 4 heads; wave h = tanh+softmax; joint readout ----
__global__ __launch_bounds__(256) void k2(const float* __restrict__ s1pp,
                                          const float* __restrict__ s2pp,
                                          const float* __restrict__ X1,
                                          const float* __restrict__ X2,
                                          float* __restrict__ out,
                                          float* __restrict__ rws) {
  __shared__ float aL[4][512];
  __shared__ f32x4 redv[4][8][32];
  int side = blockIdx.x >> 6, b = blockIdx.x & 63;
  int t = threadIdx.x, ln = t & 63, h = t >> 6;
  int bh = b * 4 + h;
  int base = ln * 8;

  float vals[8];
  if (side == 0) {
    int lt = base >> 7, r = base & 127;
    const float* p0 = s1pp + (((size_t)bh * 4 + lt) * 2) * 128 + r;
#pragma unroll
    for (int q = 0; q < 8; q += 4) {
      float4 va = *(const float4*)(p0 + q);
      float4 vb = *(const float4*)(p0 + 128 + q);
      vals[q + 0] = fmaxf(va.x, vb.x);
      vals[q + 1] = fmaxf(va.y, vb.y);
      vals[q + 2] = fmaxf(va.z, vb.z);
      vals[q + 3] = fmaxf(va.w, vb.w);
    }
  } else {
#pragma unroll
    for (int q = 0; q < 8; ++q) vals[q] = -3.0e38f;
#pragma unroll
    for (int sl = 0; sl < 8; ++sl) {
      const float* p = s2pp + (((size_t)bh * 4 + (sl >> 1)) * 2 + (sl & 1)) * 512 + base;
#pragma unroll
      for (int q = 0; q < 8; q += 4) {
        float4 v = *(const float4*)(p + q);
        vals[q + 0] = fmaxf(vals[q + 0], v.x);
        vals[q + 1] = fmaxf(vals[q + 1], v.y);
        vals[q + 2] = fmaxf(vals[q + 2], v.z);
        vals[q + 3] = fmaxf(vals[q + 3], v.w);
      }
    }
  }
#pragma unroll
  for (int q = 0; q < 8; ++q) vals[q] = tanhf(vals[q]);
  float mx = vals[0];
#pragma unroll
  for (int q = 1; q < 8; ++q) mx = fmaxf(mx, vals[q]);
#pragma unroll
  for (int off = 1; off < 64; off <<= 1) mx = fmaxf(mx, __shfl_xor(mx, off));
  float s = 0.0f;
#pragma unroll
  for (int q = 0; q < 8; ++q) {
    vals[q] = expf(vals[q] - mx);
    s += vals[q];
  }
#pragma unroll
  for (int off = 1; off < 64; off <<= 1) s += __shfl_xor(s, off);
  float inv = 1.0f / s;
#pragma unroll
  for (int q = 0; q < 8; ++q) vals[q] *= inv;

  int aoff = (side == 0 ? 16384 : 147456) + bh * 512 + base;
  *(float4*)(out + aoff) = make_float4(vals[0], vals[1], vals[2], vals[3]);
  *(float4*)(out + aoff + 4) = make_float4(vals[4], vals[5], vals[6], vals[7]);
  *(float4*)(&aL[h][base]) = make_float4(vals[0], vals[1], vals[2], vals[3]);
  *(float4*)(&aL[h][base + 4]) = make_float4(vals[4], vals[5], vals[6], vals[7]);
  __syncthreads();

  // readout: r[h][d] = sum_l aL[h][l] * X[l][b][d]
  const float4* X4 = (const float4*)(side == 0 ? X1 : X2);
  int q = t & 31, lg = t >> 5;
  f32x4 av[4];
  const f32x4 fz = {0.f, 0.f, 0.f, 0.f};
#pragma unroll
  for (int hh = 0; hh < 4; ++hh) av[hh] = fz;
  for (int l = lg; l < 512; l += 8) {
    float4 xv = X4[((size_t)l * Bn + b) * 32 + q];
#pragma unroll
    for (int hh = 0; hh < 4; ++hh) {
      float w = aL[hh][l];
      av[hh][0] += w * xv.x;
      av[hh][1] += w * xv.y;
      av[hh][2] += w * xv.z;
      av[hh][3] += w * xv.w;
    }
  }
#pragma unroll
  for (int hh = 0; hh < 4; ++hh) redv[hh][lg][q] = av[hh];
  __syncthreads();
  if (t < 128) {
    int d = t;
#pragma unroll
    for (int hh = 0; hh < 4; ++hh) {
      float s2 = 0.0f;
#pragma unroll
      for (int g = 0; g < 8; ++g) s2 += ((const float*)&redv[hh][g][d >> 2])[d & 3];
      rws[side * 32768 + (b * 4 + hh) * 128 + d] = s2;
    }
  }
}

// ---- k3: combine hops ----
__global__ __launch_bounds__(128) void k3(const float* __restrict__ rws,
                                          const float* __restrict__ Wipm,
                                          float* __restrict__ out) {
  int b = blockIdx.x, t = threadIdx.x;  // t = d
  __shared__ float r2l[4][128];
  __shared__ float tsum[2][4];
  float r1h[4], r2h[4];
#pragma unroll
  for (int h = 0; h < 4; ++h) {
    r1h[h] = rws[(b * 4 + h) * 128 + t];
    r2h[h] = rws[32768 + (b * 4 + h) * 128 + t];
    r2l[h][t] = r2h[h];
  }
  __syncthreads();
  float p[4] = {0, 0, 0, 0};
  for (int e = 0; e < 128; ++e) {
    float w = Wipm[t * 128 + e];
#pragma unroll
    for (int h = 0; h < 4; ++h) p[h] += w * r2l[h][e];
  }
#pragma unroll
  for (int h = 0; h < 4; ++h) p[h] *= r1h[h];
#pragma unroll
  for (int off = 1; off < 64; off <<= 1)
#pragma unroll
    for (int h = 0; h < 4; ++h) p[h] += __shfl_xor(p[h], off);
  if ((t & 63) == 0)
#pragma unroll
    for (int h = 0; h < 4; ++h) tsum[t >> 6][h] = p[h];
  __syncthreads();
  float ad[4], mx = -3.0e38f;
#pragma unroll
  for (int h = 0; h < 4; ++h) {
    float v = tanhf(tsum[0][h] + tsum[1][h]);
    ad[h] = v;
    mx = fmaxf(mx, v);
  }
  float s = 0.0f;
#pragma unroll
  for (int h = 0; h < 4; ++h) { ad[h] = expf(ad[h] - mx); s += ad[h]; }
  float inv = 1.0f / s;
#pragma unroll
  for (int h = 0; h < 4; ++h) ad[h] *= inv;
  if (t < 4) out[278528 + b * 4 + t] = ad[t];
  float f1 = 0.0f, f2 = 0.0f;
#pragma unroll
  for (int h = 0; h < 4; ++h) { f1 += ad[h] * r1h[h]; f2 += ad[h] * r2h[h]; }
  out[b * 128 + t] = f1;
  out[8192 + b * 128 + t] = f2;
}

extern "C" void kernel_launch(void* const* d_in, const int* in_sizes, int n_in,
                              void* d_out, int out_size, void* d_ws,
                              size_t ws_size, hipStream_t stream) {
  (void)in_sizes; (void)n_in; (void)out_size; (void)ws_size;
  const float* x1 = (const float*)d_in[0];
  const float* x2 = (const float*)d_in[1];
  const int* raw1 = (const int*)d_in[2];
  const int* raw2 = (const int*)d_in[3];
  const float* wu = (const float*)d_in[4];
  const float* wipm = (const float*)d_in[5];
  float* out = (float*)d_out;
  unsigned short* zimg = (unsigned short*)d_ws;      // 64 MiB
  float* s1pp = (float*)((char*)d_ws + 67108864);    // 1 MiB  [bh][lt][cb][128]
  float* s2pp = (float*)((char*)d_ws + 68157440);    // 4 MiB  [bh][lt][rg][512]
  float* rws = (float*)((char*)d_ws + 72351744);     // 256 KiB [side][bh][128]

  kz<<<1024, 256, 0, stream>>>(x2, wu, zimg);
  k1<<<1024, 256, 0, stream>>>(x1, zimg, raw1, raw2, s1pp, s2pp);
  k2<<<128, 256, 0, stream>>>(s1pp, s2pp, x1, x2, out, rws);
  k3<<<64, 128, 0, stream>>>(rws, wipm, out);
}